// Round 1
// baseline (822.990 us; speedup 1.0000x reference)
//
#include <hip/hip_runtime.h>

// Problem constants
#define BB 128   // batch
#define NN 2048  // total selects
#define CC 512   // fpn size
#define JJ 64    // joints
#define QQ 128   // C/4
#define KK 200   // classes

using bf16x8  = __attribute__((ext_vector_type(8))) __bf16;
using floatx4 = __attribute__((ext_vector_type(4))) float;

__device__ __forceinline__ ushort f2bf(float f) {
    __bf16 h = (__bf16)f;                 // RNE convert
    return __builtin_bit_cast(ushort, h);
}

__device__ __forceinline__ bf16x8 ldg8(const ushort* p) {  // 16B-aligned global
    uint4 v = *(const uint4*)p;
    return __builtin_bit_cast(bf16x8, v);
}

__device__ __forceinline__ bf16x8 ldlds8(const ushort* p) { // only 4B alignment guaranteed
    struct U4 { unsigned a, b, c, d; } v;
    v.a = *(const unsigned*)(p + 0);
    v.b = *(const unsigned*)(p + 2);
    v.c = *(const unsigned*)(p + 4);
    v.d = *(const unsigned*)(p + 6);
    return __builtin_bit_cast(bf16x8, v);
}

// ---------------------------------------------------------------------------
// K0: weight prep. bf16-pack w_pool0 & w_conv1, transpose w_cls, column-means
// of w_q/w_k, means of b_q/b_k.
// ---------------------------------------------------------------------------
__global__ void k0_prep(const float* __restrict__ w_pool0, const float* __restrict__ w_conv1,
                        const float* __restrict__ w_cls, const float* __restrict__ w_q,
                        const float* __restrict__ b_q, const float* __restrict__ w_k,
                        const float* __restrict__ b_k,
                        ushort* __restrict__ w0b, ushort* __restrict__ wcb,
                        float* __restrict__ wclsT, float* __restrict__ wqm,
                        float* __restrict__ wkm, float* __restrict__ scal) {
    int gid = blockIdx.x * 256 + threadIdx.x;
    if (gid < JJ * NN) { w0b[gid] = f2bf(w_pool0[gid]); return; }
    gid -= JJ * NN;
    if (gid < CC * CC) { wcb[gid] = f2bf(w_conv1[gid]); return; }
    gid -= CC * CC;
    if (gid < CC * KK) {  // wclsT[c*200+k] = w_cls[k*512+c]
        int c = gid / KK; int k = gid - c * KK;
        wclsT[gid] = w_cls[k * CC + c];
        return;
    }
    gid -= CC * KK;
    if (gid < 2 * CC) {
        int c = gid & (CC - 1);
        const float* src = (gid < CC) ? w_q : w_k;
        float s = 0.f;
        for (int q = 0; q < QQ; ++q) s += src[q * CC + c];
        ((gid < CC) ? wqm : wkm)[c] = s * (1.f / QQ);
        return;
    }
    gid -= 2 * CC;
    if (gid == 0) { float s = 0; for (int q = 0; q < QQ; ++q) s += b_q[q]; scal[0] = s * (1.f / QQ); }
    else if (gid == 1) { float s = 0; for (int q = 0; q < QQ; ++q) s += b_k[q]; scal[1] = s * (1.f / QQ); }
}

// ---------------------------------------------------------------------------
// K1: hsT[b,j,c] = sum_n w_pool0[j,n] * x[b,n,c] + b_pool0[j]  (bf16 out)
// Block: (b, c-tile of 64). 256 thr / 4 waves; wave w owns c [w*16, w*16+16).
// x tile (32n x 64c fp32) staged to LDS transposed [c][k] bf16, pitch 34.
// ---------------------------------------------------------------------------
__global__ __launch_bounds__(256, 4) void k1_gemm(const float* __restrict__ x,
                                                  const float* __restrict__ b_pool0,
                                                  const ushort* __restrict__ w0b,
                                                  ushort* __restrict__ hsT) {
    __shared__ ushort xlds[64 * 34];    // [c][k], pitch 34 (32 k + 2 pad)
    __shared__ ushort outlds[64 * 66];  // [j][c], pitch 66 (64 c + 2 pad)

    const int blk = blockIdx.x;
    const int b = blk >> 3;
    const int c0 = (blk & 7) << 6;
    const int t = threadIdx.x;
    const int w = t >> 6, l = t & 63, lo = l & 15, quad = l >> 4;

    floatx4 acc[4];
#pragma unroll
    for (int m = 0; m < 4; ++m) acc[m] = (floatx4){0.f, 0.f, 0.f, 0.f};

    const int srow = t >> 5;          // 0..7
    const int scol = (t & 31) * 2;    // 0..62
    const float* xbase = x + (size_t)b * NN * CC + c0;

    for (int ks = 0; ks < NN / 32; ++ks) {
        const int k0 = ks * 32;
        __syncthreads();
#pragma unroll
        for (int r = 0; r < 4; ++r) {
            int n = srow + r * 8;
            const float2 v = *(const float2*)(xbase + (size_t)(k0 + n) * CC + scol);
            xlds[(scol + 0) * 34 + n] = f2bf(v.x);
            xlds[(scol + 1) * 34 + n] = f2bf(v.y);
        }
        __syncthreads();
        const int kk = k0 + quad * 8;
        bf16x8 afr[4];
#pragma unroll
        for (int m = 0; m < 4; ++m)
            afr[m] = ldg8(w0b + (size_t)(m * 16 + lo) * NN + kk);
        const bf16x8 bfr = ldlds8(xlds + (w * 16 + lo) * 34 + quad * 8);
#pragma unroll
        for (int m = 0; m < 4; ++m)
            acc[m] = __builtin_amdgcn_mfma_f32_16x16x32_bf16(afr[m], bfr, acc[m], 0, 0, 0);
    }

    // epilogue: +b_pool0, bf16, LDS transpose, coalesced store
    __syncthreads();
#pragma unroll
    for (int m = 0; m < 4; ++m) {
#pragma unroll
        for (int r = 0; r < 4; ++r) {
            int j = m * 16 + quad * 4 + r;
            float v = acc[m][r] + b_pool0[j];
            outlds[j * 66 + w * 16 + lo] = f2bf(v);
        }
    }
    __syncthreads();
    const size_t obase = (size_t)b * JJ * CC + c0;
#pragma unroll
    for (int it = 0; it < 8; ++it) {
        int dwid = it * 256 + t;
        int j = dwid >> 5, cd = (dwid & 31) * 2;
        unsigned v = *(const unsigned*)(outlds + j * 66 + cd);
        *(unsigned*)(hsT + obase + (size_t)j * CC + cd) = v;
    }
}

// ---------------------------------------------------------------------------
// K3: per (b, o-tile of 128):
//   stage1: hs2T[j,o] = sum_c hsT[b,j,c]*w_conv1[o,c] + b_conv1[o]   (MFMA)
//   fused : q1/k1 row dots (wave 0), A1T = adj1^T + tanh(q1-k1)*alpha (LDS)
//   stage2: hs3T[j,o] = sum_k A1T[j,k]*hs2T[k,o]                     (MFMA)
//   out   : atomic BN sums per o; P[b,o] = sum_j hs3T[j,o]*w_pool1[j]
// ---------------------------------------------------------------------------
__global__ __launch_bounds__(256) void k3_mid(const ushort* __restrict__ hsT,
                                              const ushort* __restrict__ wcb,
                                              const float* __restrict__ wqm,
                                              const float* __restrict__ wkm,
                                              const float* __restrict__ scal,
                                              const float* __restrict__ adj1,
                                              const float* __restrict__ alpha1,
                                              const float* __restrict__ b_conv1,
                                              const float* __restrict__ w_pool1,
                                              float* __restrict__ P,
                                              float* __restrict__ bn_sum,
                                              float* __restrict__ bn_sq) {
    __shared__ float q1s[64], k1s[64], w1s[64];
    __shared__ ushort a1t[64 * 66];    // [j][k]
    __shared__ ushort lds2[128 * 66];  // [o_local][k=j'] (hs2T transposed for B-frags)

    const int blk = blockIdx.x;
    const int b = blk >> 2;
    const int o0 = (blk & 3) << 7;
    const int t = threadIdx.x;
    const int w = t >> 6, l = t & 63, lo = l & 15, quad = l >> 4;

    if (t < JJ) w1s[t] = w_pool1[t];

    floatx4 acc[4][2];
#pragma unroll
    for (int m = 0; m < 4; ++m)
#pragma unroll
        for (int u = 0; u < 2; ++u) acc[m][u] = (floatx4){0.f, 0.f, 0.f, 0.f};
    float qp[4] = {0.f, 0.f, 0.f, 0.f}, kp[4] = {0.f, 0.f, 0.f, 0.f};

    const ushort* hb = hsT + (size_t)b * JJ * CC;
    for (int ks = 0; ks < CC / 32; ++ks) {
        const int kk = ks * 32 + quad * 8;
        bf16x8 afr[4];
#pragma unroll
        for (int m = 0; m < 4; ++m)
            afr[m] = ldg8(hb + (size_t)(m * 16 + lo) * CC + kk);
        bf16x8 bfr[2];
#pragma unroll
        for (int u = 0; u < 2; ++u) {
            int o = o0 + w * 32 + u * 16 + lo;
            bfr[u] = ldg8(wcb + (size_t)o * CC + kk);
        }
        if (w == 0) {  // wave 0 accumulates q1/k1 partials (identical A-frags per wave)
            float wqv[8], wkv[8];
            *(float4*)&wqv[0] = *(const float4*)(wqm + kk);
            *(float4*)&wqv[4] = *(const float4*)(wqm + kk + 4);
            *(float4*)&wkv[0] = *(const float4*)(wkm + kk);
            *(float4*)&wkv[4] = *(const float4*)(wkm + kk + 4);
#pragma unroll
            for (int m = 0; m < 4; ++m)
#pragma unroll
                for (int i = 0; i < 8; ++i) {
                    float av = (float)afr[m][i];
                    qp[m] += av * wqv[i];
                    kp[m] += av * wkv[i];
                }
        }
#pragma unroll
        for (int m = 0; m < 4; ++m)
#pragma unroll
            for (int u = 0; u < 2; ++u)
                acc[m][u] = __builtin_amdgcn_mfma_f32_16x16x32_bf16(afr[m], bfr[u], acc[m][u], 0, 0, 0);
    }

    if (w == 0) {
#pragma unroll
        for (int m = 0; m < 4; ++m) {
            qp[m] += __shfl_xor(qp[m], 16); qp[m] += __shfl_xor(qp[m], 32);
            kp[m] += __shfl_xor(kp[m], 16); kp[m] += __shfl_xor(kp[m], 32);
        }
        if (t < 16) {
#pragma unroll
            for (int m = 0; m < 4; ++m) {
                q1s[m * 16 + lo] = qp[m] + scal[0];
                k1s[m * 16 + lo] = kp[m] + scal[1];
            }
        }
    }

    // stage1 results -> lds2[o][j'] with conv bias
    float bc[2];
#pragma unroll
    for (int u = 0; u < 2; ++u) bc[u] = b_conv1[o0 + w * 32 + u * 16 + lo];
#pragma unroll
    for (int m = 0; m < 4; ++m)
#pragma unroll
        for (int u = 0; u < 2; ++u)
#pragma unroll
            for (int r = 0; r < 4; ++r) {
                int jj = m * 16 + quad * 4 + r;
                int ol = w * 32 + u * 16 + lo;
                lds2[ol * 66 + jj] = f2bf(acc[m][u][r] + bc[u]);
            }
    __syncthreads();

    // A1T[j][k] = adj1[k,j] + tanh(q1[k]-k1[j])*alpha
    const float alpha = alpha1[0];
#pragma unroll
    for (int r = 0; r < 16; ++r) {
        int idx = r * 256 + t;
        int j = idx & 63, k = idx >> 6;
        float v = adj1[k * 64 + j] + tanhf(q1s[k] - k1s[j]) * alpha;
        a1t[j * 66 + k] = f2bf(v);
    }
    __syncthreads();

    // stage2
    floatx4 acc2[4][2];
#pragma unroll
    for (int m = 0; m < 4; ++m)
#pragma unroll
        for (int u = 0; u < 2; ++u) acc2[m][u] = (floatx4){0.f, 0.f, 0.f, 0.f};
#pragma unroll
    for (int ks = 0; ks < 2; ++ks) {
        const int kb = ks * 32 + quad * 8;
        bf16x8 a2[4];
#pragma unroll
        for (int m = 0; m < 4; ++m)
            a2[m] = ldlds8(a1t + (m * 16 + lo) * 66 + kb);
        bf16x8 b2[2];
#pragma unroll
        for (int u = 0; u < 2; ++u)
            b2[u] = ldlds8(lds2 + (w * 32 + u * 16 + lo) * 66 + kb);
#pragma unroll
        for (int m = 0; m < 4; ++m)
#pragma unroll
            for (int u = 0; u < 2; ++u)
                acc2[m][u] = __builtin_amdgcn_mfma_f32_16x16x32_bf16(a2[m], b2[u], acc2[m][u], 0, 0, 0);
    }

    // BN stats + pooled projection P
#pragma unroll
    for (int u = 0; u < 2; ++u) {
        int o = o0 + w * 32 + u * 16 + lo;
        float s1 = 0.f, s2 = 0.f, pv = 0.f;
#pragma unroll
        for (int m = 0; m < 4; ++m)
#pragma unroll
            for (int r = 0; r < 4; ++r) {
                float v = acc2[m][u][r];
                s1 += v; s2 += v * v;
                pv += v * w1s[m * 16 + quad * 4 + r];
            }
        s1 += __shfl_xor(s1, 16); s1 += __shfl_xor(s1, 32);
        s2 += __shfl_xor(s2, 16); s2 += __shfl_xor(s2, 32);
        pv += __shfl_xor(pv, 16); pv += __shfl_xor(pv, 32);
        if (quad == 0) {
            atomicAdd(&bn_sum[o], s1);
            atomicAdd(&bn_sq[o], s2);
            P[b * CC + o] = pv;
        }
    }
}

// ---------------------------------------------------------------------------
// K4: fold BN into P, classify. out[b,k] = sum_c (g_c*P[b,c]+h_c)*wclsT[c,k]+b_cls[k]
// ---------------------------------------------------------------------------
__global__ __launch_bounds__(256) void k4_cls(const float* __restrict__ P,
                                              const float* __restrict__ bn_sum,
                                              const float* __restrict__ bn_sq,
                                              const float* __restrict__ gamma,
                                              const float* __restrict__ beta,
                                              const float* __restrict__ w_pool1,
                                              const float* __restrict__ b_pool1,
                                              const float* __restrict__ wclsT,
                                              const float* __restrict__ b_cls,
                                              float* __restrict__ out) {
    __shared__ float pooled[CC];
    __shared__ float w1s[JJ];
    const int b = blockIdx.x;
    const int t = threadIdx.x;
    if (t < JJ) w1s[t] = w_pool1[t];
    __syncthreads();
    float S1 = 0.f;
#pragma unroll
    for (int j = 0; j < JJ; ++j) S1 += w1s[j];
    const float inv = 1.f / (BB * JJ);
    for (int c = t; c < CC; c += 256) {
        float mean = bn_sum[c] * inv;
        float var = bn_sq[c] * inv - mean * mean;
        float g = gamma[c] * rsqrtf(var + 1e-5f);
        float h = (beta[c] - g * mean) * S1 + b_pool1[0];
        pooled[c] = g * P[b * CC + c] + h;
    }
    __syncthreads();
    if (t < KK) {
        float acc = b_cls[t];
        for (int c = 0; c < CC; ++c) acc += pooled[c] * wclsT[c * KK + t];
        out[b * KK + t] = acc;
    }
}

// ---------------------------------------------------------------------------
// Workspace layout (bytes)
// ---------------------------------------------------------------------------
static constexpr size_t OFF_BNSUM = 0;        // 512 f
static constexpr size_t OFF_BNSQ  = 2048;     // 512 f   (memset [0,4096))
static constexpr size_t OFF_SCAL  = 4096;     // 2 f
static constexpr size_t OFF_WQM   = 4352;     // 512 f
static constexpr size_t OFF_WKM   = 6400;     // 512 f
static constexpr size_t OFF_W0B   = 8448;     // 64*2048 bf16 = 262144 B
static constexpr size_t OFF_WCB   = 270592;   // 512*512 bf16 = 524288 B
static constexpr size_t OFF_WCLST = 794880;   // 512*200 f = 409600 B
static constexpr size_t OFF_HST   = 1204480;  // 128*64*512 bf16 = 8388608 B
static constexpr size_t OFF_P     = 9593088;  // 128*512 f = 262144 B -> end 9855232

extern "C" void kernel_launch(void* const* d_in, const int* in_sizes, int n_in,
                              void* d_out, int out_size, void* d_ws, size_t ws_size,
                              hipStream_t stream) {
    const float* x       = (const float*)d_in[0];
    const float* w_pool0 = (const float*)d_in[1];
    const float* b_pool0 = (const float*)d_in[2];
    const float* adj1    = (const float*)d_in[3];
    const float* w_conv1 = (const float*)d_in[4];
    const float* b_conv1 = (const float*)d_in[5];
    const float* w_q     = (const float*)d_in[6];
    const float* b_q     = (const float*)d_in[7];
    const float* w_k     = (const float*)d_in[8];
    const float* b_k     = (const float*)d_in[9];
    const float* alpha1  = (const float*)d_in[10];
    const float* gamma   = (const float*)d_in[11];
    const float* beta    = (const float*)d_in[12];
    const float* w_pool1 = (const float*)d_in[13];
    const float* b_pool1 = (const float*)d_in[14];
    const float* w_cls   = (const float*)d_in[15];
    const float* b_cls   = (const float*)d_in[16];

    char* ws = (char*)d_ws;
    float*  bn_sum = (float*)(ws + OFF_BNSUM);
    float*  bn_sq  = (float*)(ws + OFF_BNSQ);
    float*  scal   = (float*)(ws + OFF_SCAL);
    float*  wqm    = (float*)(ws + OFF_WQM);
    float*  wkm    = (float*)(ws + OFF_WKM);
    ushort* w0b    = (ushort*)(ws + OFF_W0B);
    ushort* wcb    = (ushort*)(ws + OFF_WCB);
    float*  wclsT  = (float*)(ws + OFF_WCLST);
    ushort* hsT    = (ushort*)(ws + OFF_HST);
    float*  P      = (float*)(ws + OFF_P);
    float*  out    = (float*)d_out;

    hipMemsetAsync(ws, 0, 4096, stream);  // bn_sum + bn_sq
    k0_prep<<<1941, 256, 0, stream>>>(w_pool0, w_conv1, w_cls, w_q, b_q, w_k, b_k,
                                      w0b, wcb, wclsT, wqm, wkm, scal);
    k1_gemm<<<BB * 8, 256, 0, stream>>>(x, b_pool0, w0b, hsT);
    k3_mid<<<BB * 4, 256, 0, stream>>>(hsT, wcb, wqm, wkm, scal, adj1, alpha1,
                                       b_conv1, w_pool1, P, bn_sum, bn_sq);
    k4_cls<<<BB, 256, 0, stream>>>(P, bn_sum, bn_sq, gamma, beta, w_pool1, b_pool1,
                                   wclsT, b_cls, out);
}

// Round 2
// 770.046 us; speedup vs baseline: 1.0688x; 1.0688x over previous
//
#include <hip/hip_runtime.h>

// Problem constants
#define BB 128   // batch
#define NN 2048  // total selects
#define CC 512   // fpn size
#define JJ 64    // joints
#define QQ 128   // C/4
#define KK 200   // classes

using bf16x8  = __attribute__((ext_vector_type(8))) __bf16;
using floatx4 = __attribute__((ext_vector_type(4))) float;

__device__ __forceinline__ ushort f2bf(float f) {
    __bf16 h = (__bf16)f;                 // RNE convert
    return __builtin_bit_cast(ushort, h);
}

__device__ __forceinline__ bf16x8 ldg8(const ushort* p) {  // 16B-aligned global
    uint4 v = *(const uint4*)p;
    return __builtin_bit_cast(bf16x8, v);
}

__device__ __forceinline__ bf16x8 ldlds8(const ushort* p) { // 4B alignment guaranteed
    struct U4 { unsigned a, b, c, d; } v;
    v.a = *(const unsigned*)(p + 0);
    v.b = *(const unsigned*)(p + 2);
    v.c = *(const unsigned*)(p + 4);
    v.d = *(const unsigned*)(p + 6);
    return __builtin_bit_cast(bf16x8, v);
}

// ---------------------------------------------------------------------------
// K0: weight prep. bf16-pack w_pool0 & w_conv1, transpose w_cls, column-means
// of w_q/w_k, means of b_q/b_k.
// ---------------------------------------------------------------------------
__global__ void k0_prep(const float* __restrict__ w_pool0, const float* __restrict__ w_conv1,
                        const float* __restrict__ w_cls, const float* __restrict__ w_q,
                        const float* __restrict__ b_q, const float* __restrict__ w_k,
                        const float* __restrict__ b_k,
                        ushort* __restrict__ w0b, ushort* __restrict__ wcb,
                        float* __restrict__ wclsT, float* __restrict__ wqm,
                        float* __restrict__ wkm, float* __restrict__ scal) {
    int gid = blockIdx.x * 256 + threadIdx.x;
    if (gid < JJ * NN) { w0b[gid] = f2bf(w_pool0[gid]); return; }
    gid -= JJ * NN;
    if (gid < CC * CC) { wcb[gid] = f2bf(w_conv1[gid]); return; }
    gid -= CC * CC;
    if (gid < CC * KK) {  // wclsT[c*200+k] = w_cls[k*512+c]
        int c = gid / KK; int k = gid - c * KK;
        wclsT[gid] = w_cls[k * CC + c];
        return;
    }
    gid -= CC * KK;
    if (gid < 2 * CC) {
        int c = gid & (CC - 1);
        const float* src = (gid < CC) ? w_q : w_k;
        float s = 0.f;
        for (int q = 0; q < QQ; ++q) s += src[q * CC + c];
        ((gid < CC) ? wqm : wkm)[c] = s * (1.f / QQ);
        return;
    }
    gid -= 2 * CC;
    if (gid == 0) { float s = 0; for (int q = 0; q < QQ; ++q) s += b_q[q]; scal[0] = s * (1.f / QQ); }
    else if (gid == 1) { float s = 0; for (int q = 0; q < QQ; ++q) s += b_k[q]; scal[1] = s * (1.f / QQ); }
}

// ---------------------------------------------------------------------------
// K1 v2: hsT[b,j,c] = sum_n w_pool0[j,n] * x[b,n,c] + b_pool0[j]  (bf16 out)
// Block = (b, c-tile of 128). 256 thr / 4 waves; wave w owns c [w*32, w*32+32).
// Register-prefetch + double-buffered LDS staging, ONE barrier per K-iter.
// x tile (32n x 128c fp32) -> bf16 transposed [c][n] in LDS, dword pitch 17.
// ---------------------------------------------------------------------------
__global__ __launch_bounds__(256) void k1_gemm(const float* __restrict__ x,
                                               const float* __restrict__ b_pool0,
                                               const ushort* __restrict__ w0b,
                                               ushort* __restrict__ hsT) {
    __shared__ unsigned xs[2][128 * 17];  // [buf][c*17 + n/2] packed bf16 pairs

    const int blk = blockIdx.x;
    const int b = blk >> 2;
    const int c0 = (blk & 3) << 7;
    const int t = threadIdx.x;
    const int w = t >> 6, l = t & 63, lo = l & 15, quad = l >> 4;

    const int cq = t & 31;     // c quad index: c_local = 4*cq + j
    const int nb = t >> 5;     // 0..7; pair index pi = nb + 8p

    floatx4 acc[4][2];
#pragma unroll
    for (int m = 0; m < 4; ++m)
#pragma unroll
        for (int u = 0; u < 2; ++u) acc[m][u] = (floatx4){0.f, 0.f, 0.f, 0.f};

    const float* xb = x + (size_t)b * NN * CC + c0 + 4 * cq;

    float4 ra[2], rb[2];
    auto issue = [&](int n0) {
#pragma unroll
        for (int p = 0; p < 2; ++p) {
            const int pi = nb + p * 8;
            ra[p] = *(const float4*)(xb + (size_t)(n0 + 2 * pi) * CC);
            rb[p] = *(const float4*)(xb + (size_t)(n0 + 2 * pi + 1) * CC);
        }
    };
    auto commit = [&](int buf) {
#pragma unroll
        for (int p = 0; p < 2; ++p) {
            const int pi = nb + p * 8;
#pragma unroll
            for (int j = 0; j < 4; ++j) {
                unsigned lo16 = f2bf(((const float*)&ra[p])[j]);
                unsigned hi16 = f2bf(((const float*)&rb[p])[j]);
                xs[buf][(4 * cq + j) * 17 + pi] = lo16 | (hi16 << 16);
            }
        }
    };

    issue(0);
    commit(0);
    __syncthreads();

    for (int ks = 0; ks < NN / 32; ++ks) {
        const int cur = ks & 1;
        if (ks < NN / 32 - 1) issue((ks + 1) * 32);

        const int kk = ks * 32 + quad * 8;
        bf16x8 afr[4];
#pragma unroll
        for (int m = 0; m < 4; ++m)
            afr[m] = ldg8(w0b + (size_t)(m * 16 + lo) * NN + kk);
        bf16x8 bfr[2];
#pragma unroll
        for (int u = 0; u < 2; ++u)
            bfr[u] = ldlds8((const ushort*)&xs[cur][(w * 32 + u * 16 + lo) * 17] + quad * 8);
#pragma unroll
        for (int m = 0; m < 4; ++m)
#pragma unroll
            for (int u = 0; u < 2; ++u)
                acc[m][u] = __builtin_amdgcn_mfma_f32_16x16x32_bf16(afr[m], bfr[u], acc[m][u], 0, 0, 0);

        if (ks < NN / 32 - 1) commit(cur ^ 1);
        __syncthreads();
    }

    // epilogue: +b_pool0, bf16, LDS transpose (reuse stage buffers), coalesced store
    ushort* outl = (ushort*)&xs[0][0];  // [j][c_local], pitch 130 u16 (65 dw) = 16.6 KB
#pragma unroll
    for (int m = 0; m < 4; ++m) {
        const float4 bias = *(const float4*)(b_pool0 + m * 16 + quad * 4);
#pragma unroll
        for (int u = 0; u < 2; ++u)
#pragma unroll
            for (int r = 0; r < 4; ++r) {
                int j = m * 16 + quad * 4 + r;
                int cl = w * 32 + u * 16 + lo;
                outl[j * 130 + cl] = f2bf(acc[m][u][r] + ((const float*)&bias)[r]);
            }
    }
    __syncthreads();
    const size_t obase = (size_t)b * JJ * CC + c0;
#pragma unroll
    for (int it = 0; it < 16; ++it) {
        int dwid = it * 256 + t;
        int j = dwid >> 6, cd = dwid & 63;
        unsigned v = ((const unsigned*)outl)[j * 65 + cd];
        *(unsigned*)(hsT + obase + (size_t)j * CC + 2 * cd) = v;
    }
}

// ---------------------------------------------------------------------------
// K3: per (b, o-tile of 128):
//   stage1: hs2T[j,o] = sum_c hsT[b,j,c]*w_conv1[o,c] + b_conv1[o]   (MFMA)
//   fused : q1/k1 row dots (wave 0), A1T = adj1^T + tanh(q1-k1)*alpha (LDS)
//   stage2: hs3T[j,o] = sum_k A1T[j,k]*hs2T[k,o]                     (MFMA)
//   out   : atomic BN sums per o; P[b,o] = sum_j hs3T[j,o]*w_pool1[j]
// ---------------------------------------------------------------------------
__global__ __launch_bounds__(256) void k3_mid(const ushort* __restrict__ hsT,
                                              const ushort* __restrict__ wcb,
                                              const float* __restrict__ wqm,
                                              const float* __restrict__ wkm,
                                              const float* __restrict__ scal,
                                              const float* __restrict__ adj1,
                                              const float* __restrict__ alpha1,
                                              const float* __restrict__ b_conv1,
                                              const float* __restrict__ w_pool1,
                                              float* __restrict__ P,
                                              float* __restrict__ bn_sum,
                                              float* __restrict__ bn_sq) {
    __shared__ float q1s[64], k1s[64], w1s[64];
    __shared__ ushort a1t[64 * 66];    // [j][k]
    __shared__ ushort lds2[128 * 66];  // [o_local][k=j'] (hs2T transposed for B-frags)

    const int blk = blockIdx.x;
    const int b = blk >> 2;
    const int o0 = (blk & 3) << 7;
    const int t = threadIdx.x;
    const int w = t >> 6, l = t & 63, lo = l & 15, quad = l >> 4;

    if (t < JJ) w1s[t] = w_pool1[t];

    floatx4 acc[4][2];
#pragma unroll
    for (int m = 0; m < 4; ++m)
#pragma unroll
        for (int u = 0; u < 2; ++u) acc[m][u] = (floatx4){0.f, 0.f, 0.f, 0.f};
    float qp[4] = {0.f, 0.f, 0.f, 0.f}, kp[4] = {0.f, 0.f, 0.f, 0.f};

    const ushort* hb = hsT + (size_t)b * JJ * CC;
    for (int ks = 0; ks < CC / 32; ++ks) {
        const int kk = ks * 32 + quad * 8;
        bf16x8 afr[4];
#pragma unroll
        for (int m = 0; m < 4; ++m)
            afr[m] = ldg8(hb + (size_t)(m * 16 + lo) * CC + kk);
        bf16x8 bfr[2];
#pragma unroll
        for (int u = 0; u < 2; ++u) {
            int o = o0 + w * 32 + u * 16 + lo;
            bfr[u] = ldg8(wcb + (size_t)o * CC + kk);
        }
        if (w == 0) {  // wave 0 accumulates q1/k1 partials (identical A-frags per wave)
            float wqv[8], wkv[8];
            *(float4*)&wqv[0] = *(const float4*)(wqm + kk);
            *(float4*)&wqv[4] = *(const float4*)(wqm + kk + 4);
            *(float4*)&wkv[0] = *(const float4*)(wkm + kk);
            *(float4*)&wkv[4] = *(const float4*)(wkm + kk + 4);
#pragma unroll
            for (int m = 0; m < 4; ++m)
#pragma unroll
                for (int i = 0; i < 8; ++i) {
                    float av = (float)afr[m][i];
                    qp[m] += av * wqv[i];
                    kp[m] += av * wkv[i];
                }
        }
#pragma unroll
        for (int m = 0; m < 4; ++m)
#pragma unroll
            for (int u = 0; u < 2; ++u)
                acc[m][u] = __builtin_amdgcn_mfma_f32_16x16x32_bf16(afr[m], bfr[u], acc[m][u], 0, 0, 0);
    }

    if (w == 0) {
#pragma unroll
        for (int m = 0; m < 4; ++m) {
            qp[m] += __shfl_xor(qp[m], 16); qp[m] += __shfl_xor(qp[m], 32);
            kp[m] += __shfl_xor(kp[m], 16); kp[m] += __shfl_xor(kp[m], 32);
        }
        if (t < 16) {
#pragma unroll
            for (int m = 0; m < 4; ++m) {
                q1s[m * 16 + lo] = qp[m] + scal[0];
                k1s[m * 16 + lo] = kp[m] + scal[1];
            }
        }
    }

    // stage1 results -> lds2[o][j'] with conv bias
    float bc[2];
#pragma unroll
    for (int u = 0; u < 2; ++u) bc[u] = b_conv1[o0 + w * 32 + u * 16 + lo];
#pragma unroll
    for (int m = 0; m < 4; ++m)
#pragma unroll
        for (int u = 0; u < 2; ++u)
#pragma unroll
            for (int r = 0; r < 4; ++r) {
                int jj = m * 16 + quad * 4 + r;
                int ol = w * 32 + u * 16 + lo;
                lds2[ol * 66 + jj] = f2bf(acc[m][u][r] + bc[u]);
            }
    __syncthreads();

    // A1T[j][k] = adj1[k,j] + tanh(q1[k]-k1[j])*alpha
    const float alpha = alpha1[0];
#pragma unroll
    for (int r = 0; r < 16; ++r) {
        int idx = r * 256 + t;
        int j = idx & 63, k = idx >> 6;
        float v = adj1[k * 64 + j] + tanhf(q1s[k] - k1s[j]) * alpha;
        a1t[j * 66 + k] = f2bf(v);
    }
    __syncthreads();

    // stage2
    floatx4 acc2[4][2];
#pragma unroll
    for (int m = 0; m < 4; ++m)
#pragma unroll
        for (int u = 0; u < 2; ++u) acc2[m][u] = (floatx4){0.f, 0.f, 0.f, 0.f};
#pragma unroll
    for (int ks = 0; ks < 2; ++ks) {
        const int kb = ks * 32 + quad * 8;
        bf16x8 a2[4];
#pragma unroll
        for (int m = 0; m < 4; ++m)
            a2[m] = ldlds8(a1t + (m * 16 + lo) * 66 + kb);
        bf16x8 b2[2];
#pragma unroll
        for (int u = 0; u < 2; ++u)
            b2[u] = ldlds8(lds2 + (w * 32 + u * 16 + lo) * 66 + kb);
#pragma unroll
        for (int m = 0; m < 4; ++m)
#pragma unroll
            for (int u = 0; u < 2; ++u)
                acc2[m][u] = __builtin_amdgcn_mfma_f32_16x16x32_bf16(a2[m], b2[u], acc2[m][u], 0, 0, 0);
    }

    // BN stats + pooled projection P
#pragma unroll
    for (int u = 0; u < 2; ++u) {
        int o = o0 + w * 32 + u * 16 + lo;
        float s1 = 0.f, s2 = 0.f, pv = 0.f;
#pragma unroll
        for (int m = 0; m < 4; ++m)
#pragma unroll
            for (int r = 0; r < 4; ++r) {
                float v = acc2[m][u][r];
                s1 += v; s2 += v * v;
                pv += v * w1s[m * 16 + quad * 4 + r];
            }
        s1 += __shfl_xor(s1, 16); s1 += __shfl_xor(s1, 32);
        s2 += __shfl_xor(s2, 16); s2 += __shfl_xor(s2, 32);
        pv += __shfl_xor(pv, 16); pv += __shfl_xor(pv, 32);
        if (quad == 0) {
            atomicAdd(&bn_sum[o], s1);
            atomicAdd(&bn_sq[o], s2);
            P[b * CC + o] = pv;
        }
    }
}

// ---------------------------------------------------------------------------
// K4: fold BN into P, classify. out[b,k] = sum_c (g_c*P[b,c]+h_c)*wclsT[c,k]+b_cls[k]
// ---------------------------------------------------------------------------
__global__ __launch_bounds__(256) void k4_cls(const float* __restrict__ P,
                                              const float* __restrict__ bn_sum,
                                              const float* __restrict__ bn_sq,
                                              const float* __restrict__ gamma,
                                              const float* __restrict__ beta,
                                              const float* __restrict__ w_pool1,
                                              const float* __restrict__ b_pool1,
                                              const float* __restrict__ wclsT,
                                              const float* __restrict__ b_cls,
                                              float* __restrict__ out) {
    __shared__ float pooled[CC];
    __shared__ float w1s[JJ];
    const int b = blockIdx.x;
    const int t = threadIdx.x;
    if (t < JJ) w1s[t] = w_pool1[t];
    __syncthreads();
    float S1 = 0.f;
#pragma unroll
    for (int j = 0; j < JJ; ++j) S1 += w1s[j];
    const float inv = 1.f / (BB * JJ);
    for (int c = t; c < CC; c += 256) {
        float mean = bn_sum[c] * inv;
        float var = bn_sq[c] * inv - mean * mean;
        float g = gamma[c] * rsqrtf(var + 1e-5f);
        float h = (beta[c] - g * mean) * S1 + b_pool1[0];
        pooled[c] = g * P[b * CC + c] + h;
    }
    __syncthreads();
    if (t < KK) {
        float acc = b_cls[t];
        for (int c = 0; c < CC; ++c) acc += pooled[c] * wclsT[c * KK + t];
        out[b * KK + t] = acc;
    }
}

// ---------------------------------------------------------------------------
// Workspace layout (bytes)
// ---------------------------------------------------------------------------
static constexpr size_t OFF_BNSUM = 0;        // 512 f
static constexpr size_t OFF_BNSQ  = 2048;     // 512 f   (memset [0,4096))
static constexpr size_t OFF_SCAL  = 4096;     // 2 f
static constexpr size_t OFF_WQM   = 4352;     // 512 f
static constexpr size_t OFF_WKM   = 6400;     // 512 f
static constexpr size_t OFF_W0B   = 8448;     // 64*2048 bf16 = 262144 B
static constexpr size_t OFF_WCB   = 270592;   // 512*512 bf16 = 524288 B
static constexpr size_t OFF_WCLST = 794880;   // 512*200 f = 409600 B
static constexpr size_t OFF_HST   = 1204480;  // 128*64*512 bf16 = 8388608 B
static constexpr size_t OFF_P     = 9593088;  // 128*512 f = 262144 B -> end 9855232

extern "C" void kernel_launch(void* const* d_in, const int* in_sizes, int n_in,
                              void* d_out, int out_size, void* d_ws, size_t ws_size,
                              hipStream_t stream) {
    const float* x       = (const float*)d_in[0];
    const float* w_pool0 = (const float*)d_in[1];
    const float* b_pool0 = (const float*)d_in[2];
    const float* adj1    = (const float*)d_in[3];
    const float* w_conv1 = (const float*)d_in[4];
    const float* b_conv1 = (const float*)d_in[5];
    const float* w_q     = (const float*)d_in[6];
    const float* b_q     = (const float*)d_in[7];
    const float* w_k     = (const float*)d_in[8];
    const float* b_k     = (const float*)d_in[9];
    const float* alpha1  = (const float*)d_in[10];
    const float* gamma   = (const float*)d_in[11];
    const float* beta    = (const float*)d_in[12];
    const float* w_pool1 = (const float*)d_in[13];
    const float* b_pool1 = (const float*)d_in[14];
    const float* w_cls   = (const float*)d_in[15];
    const float* b_cls   = (const float*)d_in[16];

    char* ws = (char*)d_ws;
    float*  bn_sum = (float*)(ws + OFF_BNSUM);
    float*  bn_sq  = (float*)(ws + OFF_BNSQ);
    float*  scal   = (float*)(ws + OFF_SCAL);
    float*  wqm    = (float*)(ws + OFF_WQM);
    float*  wkm    = (float*)(ws + OFF_WKM);
    ushort* w0b    = (ushort*)(ws + OFF_W0B);
    ushort* wcb    = (ushort*)(ws + OFF_WCB);
    float*  wclsT  = (float*)(ws + OFF_WCLST);
    ushort* hsT    = (ushort*)(ws + OFF_HST);
    float*  P      = (float*)(ws + OFF_P);
    float*  out    = (float*)d_out;

    hipMemsetAsync(ws, 0, 4096, stream);  // bn_sum + bn_sq
    k0_prep<<<1941, 256, 0, stream>>>(w_pool0, w_conv1, w_cls, w_q, b_q, w_k, b_k,
                                      w0b, wcb, wclsT, wqm, wkm, scal);
    k1_gemm<<<BB * 4, 256, 0, stream>>>(x, b_pool0, w0b, hsT);
    k3_mid<<<BB * 4, 256, 0, stream>>>(hsT, wcb, wqm, wkm, scal, adj1, alpha1,
                                       b_conv1, w_pool1, P, bn_sum, bn_sq);
    k4_cls<<<BB, 256, 0, stream>>>(P, bn_sum, bn_sq, gamma, beta, w_pool1, b_pool1,
                                   wclsT, b_cls, out);
}